// Round 6
// baseline (1086.870 us; speedup 1.0000x reference)
//
#include <hip/hip_runtime.h>
#include <hip/hip_cooperative_groups.h>

namespace cg = cooperative_groups;

#define HH 192
#define WW 192
#define BATCH 16
#define PLANE (HH*WW)              /* 36864 */
#define NELEM (BATCH*2*PLANE)      /* 1179648 */

// Full-width strip tiles: 192 wide x 12 tall. 16 strips x 16 batches = 256
// blocks = 1 block/CU (cooperative co-residency trivially satisfied).
// 256 threads, 9 px/thread: 3 column-groups (c, c+64, c+128) x 3 rows.
#define TILEY 12
#define SW 196   /* 192 + 4 halo cols (periodic wrap duplicated) */
#define SH 16    /* 12 + 4 halo rows */
#define SHMEM_BYTES (2*SH*SW*4)    /* 25088 B dynamic LDS */

#define SHV(ch,row,col) shp[((ch)*SH + (row))*SW + (col)]

// K8T layout: tap-major [25][8]. j<6: kernels[j]*DX^-ord; j==6: -K[1] x-flip;
// j==7: -K[2] y-flip.
__global__ void prep_kernel(const float* __restrict__ kern, float* __restrict__ K8T) {
    int t = blockIdx.x * blockDim.x + threadIdx.x;
    if (t >= 200) return;
    const float inv  = 1.0f / 0.0327249f;
    const float inv2 = inv * inv;
    const float sc[6] = {1.0f, inv, inv, inv2, inv2, inv2};
    int o = t / 8, j = t % 8, dy = o / 5, dx = o % 5;
    float v;
    if (j < 6)       v =  kern[j*25 + dy*5 + dx] * sc[j];
    else if (j == 6) v = -kern[1*25 + dy*5 + (4-dx)] * sc[1];
    else             v = -kern[2*25 + (4-dy)*5 + dx] * sc[2];
    K8T[o*8 + j] = v;
}

#define ZF(p,i) D[p][(i)/6][(i)%6]

// One RHS phase: stage strip to LDS, conv (8 stencils x 2 ch), upwind-select
// via analytic poly gradient, poly forward, axpy store.
// CEN_LDS: axpy base == staged field -> read center from LDS (skip cglob).
// NOTE: LDS accessed via extern __shared__ INSIDE this function (never passed
// as a generic pointer arg) and no pointer-null tests — both work around a
// gfx950 backend bug (illegal V_CMP vs $src_shared_base).
template<bool CEN_LDS>
__device__ __forceinline__ void phase_body(
    const float* __restrict__ sstage, const float* __restrict__ cglob,
    float* __restrict__ dst, float alpha,
    const float* __restrict__ K8T,
    const float* __restrict__ pw0, const float* __restrict__ pb0,
    const float* __restrict__ pw1, const float* __restrict__ pb1,
    const float* __restrict__ pwf, const float* __restrict__ pbf,
    int b, int ty0, int tid)
{
    extern __shared__ float shp[];

    __syncthreads();   // LDS reuse guard (first phase: harmless)

    const float* sb = sstage + (size_t)b * 2 * PLANE;
    // Main staging: float2 pairs, LDS cols 2..193 <- gx 0..191.
    // 2ch x 16 rows x 96 pairs = 3072 pairs = 12 per thread, exact.
    #pragma unroll
    for (int it = 0; it < 12; ++it) {
        const int i   = tid + it * 256;
        const int ch  = i / (SH * 96);
        const int rem = i - ch * (SH * 96);
        const int rr  = rem / 96;
        const int pp  = rem - rr * 96;
        int gy = ty0 + rr - 2; if (gy < 0) gy += HH; if (gy >= HH) gy -= HH;
        const float2 v = *(const float2*)(sb + ch * PLANE + gy * WW + 2 * pp);
        *(float2*)(&SHV(ch, rr, 2 + 2 * pp)) = v;
    }
    // Wrap halo cols: LDS cols {0,1} <- gx {190,191}; {194,195} <- gx {0,1}.
    if (tid < 128) {
        const int ch = tid & 1, j = (tid >> 1) & 3, rr = tid >> 3;  // rr 0..15
        int gy = ty0 + rr - 2; if (gy < 0) gy += HH; if (gy >= HH) gy -= HH;
        const int lcol = (j < 2) ? j : (192 + j);
        const int gx   = (j < 2) ? (190 + j) : (j - 2);
        SHV(ch, rr, lcol) = sb[ch * PLANE + gy * WW + gx];
    }
    __syncthreads();

    const int c = tid & 63;          // column base
    const int r = tid >> 6;          // 0..3 -> rows 3r..3r+2
    float* db = dst + (size_t)b * 2 * PLANE;
    const float* cb = cglob + (size_t)b * 2 * PLANE;

    #pragma unroll 1
    for (int g = 0; g < 3; ++g) {
        const int cg2 = c + (g << 6);    // px col 0..191

        // ---- conv: D[px][ch][j]
        float D[3][2][8];
        #pragma unroll
        for (int p = 0; p < 3; ++p)
            #pragma unroll
            for (int ch = 0; ch < 2; ++ch)
                #pragma unroll
                for (int j = 0; j < 8; ++j)
                    D[p][ch][j] = 0.0f;

        #pragma unroll
        for (int ch = 0; ch < 2; ++ch) {
            float win[7][5];
            #pragma unroll
            for (int i = 0; i < 7; ++i)
                #pragma unroll
                for (int dx = 0; dx < 5; ++dx)
                    win[i][dx] = SHV(ch, 3*r + i, cg2 + dx);
            #pragma unroll
            for (int o = 0; o < 25; ++o) {
                const int dy = o / 5, dx = o % 5;
                #pragma unroll
                for (int j = 0; j < 8; ++j) {
                    const float w = K8T[o*8 + j];
                    D[0][ch][j] += win[dy][dx]   * w;
                    D[1][ch][j] += win[dy+1][dx] * w;
                    D[2][ch][j] += win[dy+2][dx] * w;
                }
            }
        }

        float xs[3][12];
        #pragma unroll
        for (int p = 0; p < 3; ++p)
            #pragma unroll
            for (int i = 0; i < 12; ++i)
                xs[p][i] = ZF(p, i);

        // ---- upwind: analytic d(poly_k)/dz at base z, 3 px lockstep
        #pragma unroll
        for (int k = 0; k < 2; ++k) {
            const float* W0 = pw0 + k*24;
            const float* B0 = pb0 + k*2;
            const float* W1 = pw1 + k*26;
            const float* B1 = pb1 + k*2;
            const float* WF = pwf + k*14;

            float o0[3], o1[3], q0[3], q1[3];
            #pragma unroll
            for (int p = 0; p < 3; ++p) { o0[p] = B0[0]; o1[p] = B0[1]; }
            #pragma unroll
            for (int i = 0; i < 12; ++i) {
                const float wa = W0[i], wb = W0[12+i];
                #pragma unroll
                for (int p = 0; p < 3; ++p) {
                    o0[p] += wa * ZF(p, i);
                    o1[p] += wb * ZF(p, i);
                }
            }
            #pragma unroll
            for (int p = 0; p < 3; ++p) {
                const float pp = o0[p]*o1[p];
                q0[p] = B1[0] + W1[12]*pp;
                q1[p] = B1[1] + W1[25]*pp;
            }
            #pragma unroll
            for (int i = 0; i < 12; ++i) {
                const float wa = W1[i], wb = W1[13+i];
                #pragma unroll
                for (int p = 0; p < 3; ++p) {
                    q0[p] += wa * ZF(p, i);
                    q1[p] += wb * ZF(p, i);
                }
            }

            const int i1 = k*6+1, i2 = k*6+2;
            #pragma unroll
            for (int p = 0; p < 3; ++p) {
                {
                    const float t = o1[p]*W0[i1] + o0[p]*W0[12+i1];
                    const float gr = WF[i1] + WF[12]*t
                        + WF[13]*(q1[p]*(W1[i1] + W1[12]*t) + q0[p]*(W1[13+i1] + W1[25]*t));
                    xs[p][i1] = (gr > 0.0f) ? ZF(p, i1) : D[p][k][6];
                }
                {
                    const float t = o1[p]*W0[i2] + o0[p]*W0[12+i2];
                    const float gr = WF[i2] + WF[12]*t
                        + WF[13]*(q1[p]*(W1[i2] + W1[12]*t) + q0[p]*(W1[13+i2] + W1[25]*t));
                    xs[p][i2] = (gr > 0.0f) ? ZF(p, i2) : D[p][k][7];
                }
            }
        }

        // ---- forward poly at selected features, 3 px lockstep
        float res[3][2];
        #pragma unroll
        for (int k = 0; k < 2; ++k) {
            const float* W0 = pw0 + k*24;
            const float* B0 = pb0 + k*2;
            const float* W1 = pw1 + k*26;
            const float* B1 = pb1 + k*2;
            const float* WF = pwf + k*14;
            const float* BF = pbf + k;

            float o0[3], o1[3], q0[3], q1[3], y[3];
            #pragma unroll
            for (int p = 0; p < 3; ++p) { o0[p] = B0[0]; o1[p] = B0[1]; }
            #pragma unroll
            for (int i = 0; i < 12; ++i) {
                const float wa = W0[i], wb = W0[12+i];
                #pragma unroll
                for (int p = 0; p < 3; ++p) {
                    o0[p] += wa * xs[p][i];
                    o1[p] += wb * xs[p][i];
                }
            }
            #pragma unroll
            for (int p = 0; p < 3; ++p) {
                const float pp = o0[p]*o1[p];
                q0[p] = B1[0] + W1[12]*pp;
                q1[p] = B1[1] + W1[25]*pp;
                y[p]  = BF[0] + WF[12]*pp;
            }
            #pragma unroll
            for (int i = 0; i < 12; ++i) {
                const float wa = W1[i], wb = W1[13+i], wc = WF[i];
                #pragma unroll
                for (int p = 0; p < 3; ++p) {
                    q0[p] += wa * xs[p][i];
                    q1[p] += wb * xs[p][i];
                    y[p]  += wc * xs[p][i];
                }
            }
            #pragma unroll
            for (int p = 0; p < 3; ++p)
                res[p][k] = y[p] + WF[13]*(q0[p]*q1[p]);
        }

        // ---- epilogue: axpy + store
        #pragma unroll
        for (int p = 0; p < 3; ++p) {
            const int gi = (ty0 + 3*r + p) * WW + cg2;
            float c0, c1;
            if (CEN_LDS) {
                c0 = SHV(0, 3*r + p + 2, cg2 + 2);
                c1 = SHV(1, 3*r + p + 2, cg2 + 2);
            } else {
                c0 = cb[gi];
                c1 = cb[gi + PLANE];
            }
            db[gi]         = c0 + alpha * res[p][0];
            db[gi + PLANE] = c1 + alpha * res[p][1];
        }
    }
}

// Cooperative: all 10 RHS evals in one kernel, grid.sync between phases.
__global__ __launch_bounds__(256, 2) void rk2_coop(
    const float* __restrict__ init, const float* __restrict__ K8T,
    float* __restrict__ U, float* __restrict__ UH, float* __restrict__ out,
    const float* __restrict__ pw0, const float* __restrict__ pb0,
    const float* __restrict__ pw1, const float* __restrict__ pb1,
    const float* __restrict__ pwf, const float* __restrict__ pbf)
{
    cg::grid_group gg = cg::this_grid();
    const int b   = blockIdx.y;
    const int ty0 = blockIdx.x * TILEY;
    const int tid = threadIdx.x;

    #pragma unroll 1
    for (int s = 0; s < 5; ++s) {
        const float* u  = (s == 0) ? init : U;
        float* dst      = (s == 4) ? out : U;
        // even phase: uh = u + 0.1*rhs(u)   (center from LDS)
        phase_body<true>(u, u, UH, 0.1f, K8T,
                         pw0, pb0, pw1, pb1, pwf, pbf, b, ty0, tid);
        __threadfence();
        gg.sync();
        __threadfence();
        // odd phase: u' = u + 0.2*rhs(uh)   (center from global u)
        phase_body<false>(UH, u, dst, 0.2f, K8T,
                          pw0, pb0, pw1, pb1, pwf, pbf, b, ty0, tid);
        if (s < 4) {
            __threadfence();
            gg.sync();
            __threadfence();
        }
    }
}

// Fallback: one phase per launch (global sync via kernel boundary).
template<bool CEN_LDS>
__global__ __launch_bounds__(256, 2) void rhs_phase(
    const float* __restrict__ sstage, const float* __restrict__ cglob,
    float* __restrict__ dst, float alpha,
    const float* __restrict__ K8T,
    const float* __restrict__ pw0, const float* __restrict__ pb0,
    const float* __restrict__ pw1, const float* __restrict__ pb1,
    const float* __restrict__ pwf, const float* __restrict__ pbf)
{
    phase_body<CEN_LDS>(sstage, cglob, dst, alpha, K8T,
                        pw0, pb0, pw1, pb1, pwf, pbf,
                        blockIdx.y, blockIdx.x * TILEY, threadIdx.x);
}

extern "C" void kernel_launch(void* const* d_in, const int* in_sizes, int n_in,
                              void* d_out, int out_size, void* d_ws, size_t ws_size,
                              hipStream_t stream)
{
    const float* init = (const float*)d_in[0];
    const float* kern = (const float*)d_in[1];
    const float* pw0  = (const float*)d_in[2];
    const float* pb0  = (const float*)d_in[3];
    const float* pw1  = (const float*)d_in[4];
    const float* pb1  = (const float*)d_in[5];
    const float* pwf  = (const float*)d_in[6];
    const float* pbf  = (const float*)d_in[7];
    float* out = (float*)d_out;

    float* K8T = (float*)d_ws;         // 200 floats (padded to 256)
    float* U   = K8T + 256;            // NELEM floats
    float* UH  = U + NELEM;            // NELEM floats

    prep_kernel<<<dim3(1), dim3(256), 0, stream>>>(kern, K8T);

    dim3 grid(HH / TILEY, BATCH);      // (16,16) = 256 blocks = 1/CU
    dim3 block(256);

    void* args[] = { (void*)&init, (void*)&K8T, (void*)&U, (void*)&UH, (void*)&out,
                     (void*)&pw0, (void*)&pb0, (void*)&pw1, (void*)&pb1,
                     (void*)&pwf, (void*)&pbf };
    hipError_t err = hipLaunchCooperativeKernel((const void*)rk2_coop, grid, block,
                                                args, SHMEM_BYTES, stream);
    if (err != hipSuccess) {
        // Fallback: 10 separate phase launches (identical math).
        for (int s = 0; s < 5; ++s) {
            const float* u = (s == 0) ? init : U;
            float* dst     = (s == 4) ? out : U;
            rhs_phase<true><<<grid, block, SHMEM_BYTES, stream>>>(
                u, u, UH, 0.1f, K8T, pw0, pb0, pw1, pb1, pwf, pbf);
            rhs_phase<false><<<grid, block, SHMEM_BYTES, stream>>>(
                UH, u, dst, 0.2f, K8T, pw0, pb0, pw1, pb1, pwf, pbf);
        }
    }
}

// Round 7
// 436.040 us; speedup vs baseline: 2.4926x; 2.4926x over previous
//
#include <hip/hip_runtime.h>

#define HH 192
#define WW 192
#define BATCH 16
#define PLANE (HH*WW)              /* 36864 */
#define NELEM (BATCH*2*PLANE)      /* 1179648 */

// Tile 64x4 px, 256 threads, 1 px/thread. Halo 2 each side.
// grid (3,48,16) = 2304 blocks; __launch_bounds__(256,6) -> 6 blocks/CU.
#define SW 68   /* 64 + 4 */
#define SH 8    /* 4 + 4 */

// K8T layout: tap-major [25][8]. j<6: kernels[j]*DX^-ord; j==6: -K[1] x-flip;
// j==7: -K[2] y-flip.
__global__ void prep_kernel(const float* __restrict__ kern, float* __restrict__ K8T) {
    int t = blockIdx.x * blockDim.x + threadIdx.x;
    if (t >= 200) return;
    const float inv  = 1.0f / 0.0327249f;
    const float inv2 = inv * inv;
    const float sc[6] = {1.0f, inv, inv, inv2, inv2, inv2};
    int o = t / 8, j = t % 8, dy = o / 5, dx = o % 5;
    float v;
    if (j < 6)       v =  kern[j*25 + dy*5 + dx] * sc[j];
    else if (j == 6) v = -kern[1*25 + dy*5 + (4-dx)] * sc[1];
    else             v = -kern[2*25 + (4-dy)*5 + dx] * sc[2];
    K8T[o*8 + j] = v;
}

// Feature i (0..11) aliases D[i/6][i%6] (compile-time i).
#define ZF(i) D[(i)/6][(i)%6]

// One RHS eval fused with axpy: uout = ubase + alpha*rhs(uin).
// CEN_LDS: ubase == uin -> read axpy center from LDS.
// 1 px/thread, minimal live registers (win reused across ch; D mutated in
// place for upwind selection; no xs copy).
template<bool CEN_LDS>
__global__ __launch_bounds__(256, 6) void rhs_phase(
    const float* __restrict__ uin,
    const float* __restrict__ cglob,
    float* __restrict__ dst, float alpha,
    const float* __restrict__ K8T,
    const float* __restrict__ pw0, const float* __restrict__ pb0,
    const float* __restrict__ pw1, const float* __restrict__ pb1,
    const float* __restrict__ pwf, const float* __restrict__ pbf)
{
    __shared__ float sh[2][SH][SW];
    const int b   = blockIdx.z;
    const int ty0 = blockIdx.y * 4;
    const int tx0 = blockIdx.x * 64;
    const int tid = threadIdx.x;

    const float* sb = uin + (size_t)b * 2 * PLANE;

    // ---- staging (all bit ops): cols 0..63 by 64x4 layout, 2 rows each;
    // cols 64..67 by first 64 threads.
    const int col = tid & 63;
    const int rg  = tid >> 6;               // 0..3
    {
        int gx = tx0 + col - 2; if (gx < 0) gx += WW;
        #pragma unroll
        for (int r2 = 0; r2 < 2; ++r2) {
            const int ly = rg + 4*r2;       // 0..7
            int gy = ty0 + ly - 2; if (gy < 0) gy += HH; if (gy >= HH) gy -= HH;
            const int gi = gy*WW + gx;
            sh[0][ly][col] = sb[gi];
            sh[1][ly][col] = sb[PLANE + gi];
        }
        if (tid < 64) {
            const int c2 = tid & 3, row = (tid >> 2) & 7, ch = tid >> 5;
            int gx2 = tx0 + 62 + c2; if (gx2 >= WW) gx2 -= WW;
            int gy = ty0 + row - 2; if (gy < 0) gy += HH; if (gy >= HH) gy -= HH;
            sh[ch][row][64 + c2] = sb[ch*PLANE + gy*WW + gx2];
        }
    }
    __syncthreads();

    // ---- conv: D[ch][j], 16 dot products; win live one channel at a time.
    float D[2][8];
    #pragma unroll
    for (int ch = 0; ch < 2; ++ch) {
        float win[5][5];
        #pragma unroll
        for (int dy = 0; dy < 5; ++dy)
            #pragma unroll
            for (int dx = 0; dx < 5; ++dx)
                win[dy][dx] = sh[ch][rg+dy][col+dx];
        #pragma unroll
        for (int j = 0; j < 8; ++j) D[ch][j] = 0.0f;
        #pragma unroll
        for (int o = 0; o < 25; ++o) {
            const float wv = win[o/5][o%5];
            #pragma unroll
            for (int j = 0; j < 8; ++j)
                D[ch][j] += wv * K8T[o*8 + j];
        }
    }

    // ---- upwind: analytic d(poly_k)/dz at base z (both k BEFORE overwrite).
    float sel[2][2];   // [k][0]=u01 sel, [k][1]=u10 sel
    #pragma unroll
    for (int k = 0; k < 2; ++k) {
        const float* W0 = pw0 + k*24;   // [2][12]
        const float* B0 = pb0 + k*2;
        const float* W1 = pw1 + k*26;   // [2][13]
        const float* B1 = pb1 + k*2;
        const float* WF = pwf + k*14;   // [14]

        float o0 = B0[0], o1 = B0[1];
        #pragma unroll
        for (int i = 0; i < 12; ++i) { o0 += W0[i]*ZF(i); o1 += W0[12+i]*ZF(i); }
        const float pp = o0*o1;
        float q0 = B1[0] + W1[12]*pp;
        float q1 = B1[1] + W1[25]*pp;
        #pragma unroll
        for (int i = 0; i < 12; ++i) { q0 += W1[i]*ZF(i); q1 += W1[13+i]*ZF(i); }

        const int i1 = k*6+1, i2 = k*6+2;
        {
            const float t = o1*W0[i1] + o0*W0[12+i1];
            const float g = WF[i1] + WF[12]*t
                + WF[13]*(q1*(W1[i1] + W1[12]*t) + q0*(W1[13+i1] + W1[25]*t));
            sel[k][0] = (g > 0.0f) ? ZF(i1) : D[k][6];
        }
        {
            const float t = o1*W0[i2] + o0*W0[12+i2];
            const float g = WF[i2] + WF[12]*t
                + WF[13]*(q1*(W1[i2] + W1[12]*t) + q0*(W1[13+i2] + W1[25]*t));
            sel[k][1] = (g > 0.0f) ? ZF(i2) : D[k][7];
        }
    }
    // Overwrite features in place (both polys see both channels' selections).
    D[0][1] = sel[0][0];  D[0][2] = sel[0][1];
    D[1][1] = sel[1][0];  D[1][2] = sel[1][1];

    // ---- forward poly at selected features.
    float res[2];
    #pragma unroll
    for (int k = 0; k < 2; ++k) {
        const float* W0 = pw0 + k*24;
        const float* B0 = pb0 + k*2;
        const float* W1 = pw1 + k*26;
        const float* B1 = pb1 + k*2;
        const float* WF = pwf + k*14;
        const float* BF = pbf + k;

        float o0 = B0[0], o1 = B0[1];
        #pragma unroll
        for (int i = 0; i < 12; ++i) { o0 += W0[i]*ZF(i); o1 += W0[12+i]*ZF(i); }
        const float pp = o0*o1;
        float q0 = B1[0] + W1[12]*pp;
        float q1 = B1[1] + W1[25]*pp;
        float y  = BF[0] + WF[12]*pp;
        #pragma unroll
        for (int i = 0; i < 12; ++i) {
            q0 += W1[i]*ZF(i);
            q1 += W1[13+i]*ZF(i);
            y  += WF[i]*ZF(i);
        }
        res[k] = y + WF[13]*(q0*q1);
    }

    // ---- epilogue: axpy + store.
    const int gi = (ty0 + rg)*WW + (tx0 + col);
    float c0, c1;
    if (CEN_LDS) {
        c0 = sh[0][rg+2][col+2];
        c1 = sh[1][rg+2][col+2];
    } else {
        const float* cb = cglob + (size_t)b * 2 * PLANE;
        c0 = cb[gi];
        c1 = cb[gi + PLANE];
    }
    float* db = dst + (size_t)b * 2 * PLANE;
    db[gi]         = c0 + alpha * res[0];
    db[gi + PLANE] = c1 + alpha * res[1];
}

extern "C" void kernel_launch(void* const* d_in, const int* in_sizes, int n_in,
                              void* d_out, int out_size, void* d_ws, size_t ws_size,
                              hipStream_t stream)
{
    const float* init = (const float*)d_in[0];
    const float* kern = (const float*)d_in[1];
    const float* pw0  = (const float*)d_in[2];
    const float* pb0  = (const float*)d_in[3];
    const float* pw1  = (const float*)d_in[4];
    const float* pb1  = (const float*)d_in[5];
    const float* pwf  = (const float*)d_in[6];
    const float* pbf  = (const float*)d_in[7];
    float* out = (float*)d_out;

    float* K8T = (float*)d_ws;         // 200 floats (padded to 256)
    float* U   = K8T + 256;            // NELEM floats
    float* UH  = U + NELEM;            // NELEM floats

    prep_kernel<<<dim3(1), dim3(256), 0, stream>>>(kern, K8T);

    dim3 grid(3, 48, BATCH);           // 64x4 tiles -> 2304 blocks
    dim3 block(256);

    // 5 RK2 midpoint steps = 10 sequential RHS evals.
    for (int s = 0; s < 5; ++s) {
        const float* u = (s == 0) ? init : U;
        float* dstF    = (s == 4) ? out : U;
        // uh = u + 0.1*rhs(u)       (axpy center from LDS)
        rhs_phase<true><<<grid, block, 0, stream>>>(
            u, u, UH, 0.1f, K8T, pw0, pb0, pw1, pb1, pwf, pbf);
        // u' = u + 0.2*rhs(uh)      (axpy center from global u)
        rhs_phase<false><<<grid, block, 0, stream>>>(
            UH, u, dstF, 0.2f, K8T, pw0, pb0, pw1, pb1, pwf, pbf);
    }
}

// Round 8
// 403.994 us; speedup vs baseline: 2.6903x; 1.0793x over previous
//
#include <hip/hip_runtime.h>

#define HH 192
#define WW 192
#define BATCH 16
#define PLANE (HH*WW)              /* 36864 */

// Padded field layout: pitch 208 (row-start 64B-aligned), 196 rows
// (2 halo top/bottom). Padded(r,c) = logical(r-2, c-2); halos hold the
// periodic wrap so conv needs NO wrap logic and NO LDS staging.
#define PW 208
#define PH 196
#define PPLANE (PW*PH)             /* 40768 */
#define PBUF (BATCH*2*PPLANE)      /* 1304576 floats = 5.2 MB */

// K8T layout: tap-major [25][8]. j<6: kernels[j]*DX^-ord; j==6: -K[1] x-flip;
// j==7: -K[2] y-flip.
__global__ void prep_kernel(const float* __restrict__ kern, float* __restrict__ K8T) {
    int t = blockIdx.x * blockDim.x + threadIdx.x;
    if (t >= 200) return;
    const float inv  = 1.0f / 0.0327249f;
    const float inv2 = inv * inv;
    const float sc[6] = {1.0f, inv, inv, inv2, inv2, inv2};
    int o = t / 8, j = t % 8, dy = o / 5, dx = o % 5;
    float v;
    if (j < 6)       v =  kern[j*25 + dy*5 + dx] * sc[j];
    else if (j == 6) v = -kern[1*25 + dy*5 + (4-dx)] * sc[1];
    else             v = -kern[2*25 + (4-dy)*5 + dx] * sc[2];
    K8T[o*8 + j] = v;
}

// Build padded copy of init (one-off; subsequent phases write padded+mirrors).
__global__ __launch_bounds__(256) void pad_field(
    const float* __restrict__ src, float* __restrict__ dstp)
{
    int t = blockIdx.x * 256 + threadIdx.x;
    if (t >= PBUF) return;
    int pc = t % PW;
    int r1 = t / PW;
    int pr = r1 % PH;
    int bc = r1 / PH;              // b*2+ch
    int lr = pr - 2; if (lr < 0) lr += HH; if (lr >= HH) lr -= HH;
    int lc = pc - 2; if (lc < 0) lc += WW; if (lc >= WW) lc -= WW;  // pc<=207 -> lc-2<=205, one sub ok
    dstp[t] = src[(size_t)bc * PLANE + lr * WW + lc];
}

// Feature i (0..11) aliases D[i/6][i%6] (compile-time i).
#define ZF(i) D[(i)/6][(i)%6]

// One RHS eval fused with axpy.
// MODE 0: even phase  — center from conv window, dst padded (+mirrors).
// MODE 1: odd middle  — center from cenp,        dst padded (+mirrors).
// MODE 2: odd final   — center from cenp,        dst raw d_out.
template<int MODE>
__global__ __launch_bounds__(256, 5) void rhs_phase(
    const float* __restrict__ srcp,    // padded conv input
    const float* __restrict__ cenp,    // padded axpy base (MODE 1/2)
    float* __restrict__ dst, float alpha,
    const float* __restrict__ K8T,
    const float* __restrict__ pw0, const float* __restrict__ pb0,
    const float* __restrict__ pw1, const float* __restrict__ pb1,
    const float* __restrict__ pwf, const float* __restrict__ pbf)
{
    const int b  = blockIdx.z;
    const int gy = blockIdx.y * 4  + (threadIdx.x >> 6);
    const int gx = blockIdx.x * 64 + (threadIdx.x & 63);
    const size_t corner = (size_t)b * 2 * PPLANE + (size_t)gy * PW + gx;

    // ---- conv: 25 imm-offset global loads per channel, 16 dot products.
    float D[2][8];
    float cen0, cen1;
    {
        const float* p0 = srcp + corner;
        float win[25];
        #pragma unroll
        for (int o = 0; o < 25; ++o) win[o] = p0[(o/5)*PW + (o%5)];
        #pragma unroll
        for (int j = 0; j < 8; ++j) D[0][j] = 0.0f;
        #pragma unroll
        for (int o = 0; o < 25; ++o)
            #pragma unroll
            for (int j = 0; j < 8; ++j)
                D[0][j] += win[o] * K8T[o*8 + j];
        cen0 = win[12];
    }
    {
        const float* p1 = srcp + corner + PPLANE;
        float win[25];
        #pragma unroll
        for (int o = 0; o < 25; ++o) win[o] = p1[(o/5)*PW + (o%5)];
        #pragma unroll
        for (int j = 0; j < 8; ++j) D[1][j] = 0.0f;
        #pragma unroll
        for (int o = 0; o < 25; ++o)
            #pragma unroll
            for (int j = 0; j < 8; ++j)
                D[1][j] += win[o] * K8T[o*8 + j];
        cen1 = win[12];
    }

    // ---- pass 1: affine sums + analytic gradient upwind at base z.
    // Carries o0,o1 (hidden-1 pre-product), ql (q linear part), ylin.
    float o0s[2], o1s[2], ql0s[2], ql1s[2], yls[2];
    float del[4];   // deltas for features 1,2 (k=0) and 7,8 (k=1)
    #pragma unroll
    for (int k = 0; k < 2; ++k) {
        const float* W0 = pw0 + k*24;   // [2][12]
        const float* B0 = pb0 + k*2;
        const float* W1 = pw1 + k*26;   // [2][13]
        const float* B1 = pb1 + k*2;
        const float* WF = pwf + k*14;   // [14]
        const float* BF = pbf + k;

        float a0 = B0[0], a1 = B0[1], l0 = B1[0], l1 = B1[1], yl = BF[0];
        #pragma unroll
        for (int i = 0; i < 12; ++i) {
            const float zi = ZF(i);
            a0 += W0[i]    * zi;
            a1 += W0[12+i] * zi;
            l0 += W1[i]    * zi;
            l1 += W1[13+i] * zi;
            yl += WF[i]    * zi;
        }
        const float p1 = a0 * a1;
        const float q0 = l0 + W1[12] * p1;
        const float q1 = l1 + W1[25] * p1;

        const int i1 = k*6+1, i2 = k*6+2;
        {
            const float t = a1*W0[i1] + a0*W0[12+i1];
            const float g = WF[i1] + WF[12]*t
                + WF[13]*(q1*(W1[i1] + W1[12]*t) + q0*(W1[13+i1] + W1[25]*t));
            del[2*k+0] = (g > 0.0f) ? 0.0f : (D[k][6] - ZF(i1));
        }
        {
            const float t = a1*W0[i2] + a0*W0[12+i2];
            const float g = WF[i2] + WF[12]*t
                + WF[13]*(q1*(W1[i2] + W1[12]*t) + q0*(W1[13+i2] + W1[25]*t));
            del[2*k+1] = (g > 0.0f) ? 0.0f : (D[k][7] - ZF(i2));
        }
        o0s[k] = a0; o1s[k] = a1; ql0s[k] = l0; ql1s[k] = l1; yls[k] = yl;
    }

    // ---- pass 2: delta-form forward (only features 1,2,7,8 changed).
    float res[2];
    #pragma unroll
    for (int k = 0; k < 2; ++k) {
        const float* W0 = pw0 + k*24;
        const float* W1 = pw1 + k*26;
        const float* WF = pwf + k*14;

        const float a0 = o0s[k] + W0[1]*del[0] + W0[2]*del[1] + W0[7]*del[2] + W0[8]*del[3];
        const float a1 = o1s[k] + W0[13]*del[0] + W0[14]*del[1] + W0[19]*del[2] + W0[20]*del[3];
        const float l0 = ql0s[k] + W1[1]*del[0] + W1[2]*del[1] + W1[7]*del[2] + W1[8]*del[3];
        const float l1 = ql1s[k] + W1[14]*del[0] + W1[15]*del[1] + W1[20]*del[2] + W1[21]*del[3];
        const float yl = yls[k] + WF[1]*del[0] + WF[2]*del[1] + WF[7]*del[2] + WF[8]*del[3];
        const float p1 = a0 * a1;
        const float q0 = l0 + W1[12] * p1;
        const float q1 = l1 + W1[25] * p1;
        res[k] = yl + WF[12]*p1 + WF[13]*(q0*q1);
    }

    // ---- epilogue.
    if (MODE != 2) {
        const size_t mi = corner + 2*PW + 2;       // padded main index
        const float c0 = (MODE == 0) ? cen0 : cenp[mi];
        const float c1 = (MODE == 0) ? cen1 : cenp[mi + PPLANE];
        const float v0 = c0 + alpha * res[0];
        const float v1 = c1 + alpha * res[1];
        dst[mi]          = v0;
        dst[mi + PPLANE] = v1;
        // periodic halo mirrors (edge threads only)
        const int ys = (gy < 2) ? HH : ((gy >= HH-2) ? -HH : 0);
        const int xs = (gx < 2) ? WW : ((gx >= WW-2) ? -WW : 0);
        if (ys) {
            dst[mi + (ptrdiff_t)ys*PW]          = v0;
            dst[mi + (ptrdiff_t)ys*PW + PPLANE] = v1;
        }
        if (xs) {
            dst[mi + xs]          = v0;
            dst[mi + xs + PPLANE] = v1;
        }
        if (ys && xs) {
            dst[mi + (ptrdiff_t)ys*PW + xs]          = v0;
            dst[mi + (ptrdiff_t)ys*PW + xs + PPLANE] = v1;
        }
    } else {
        const size_t mi = corner + 2*PW + 2;
        const size_t oi = (size_t)b * 2 * PLANE + (size_t)gy * WW + gx;
        dst[oi]         = cenp[mi]          + alpha * res[0];
        dst[oi + PLANE] = cenp[mi + PPLANE] + alpha * res[1];
    }
}

extern "C" void kernel_launch(void* const* d_in, const int* in_sizes, int n_in,
                              void* d_out, int out_size, void* d_ws, size_t ws_size,
                              hipStream_t stream)
{
    const float* init = (const float*)d_in[0];
    const float* kern = (const float*)d_in[1];
    const float* pw0  = (const float*)d_in[2];
    const float* pb0  = (const float*)d_in[3];
    const float* pw1  = (const float*)d_in[4];
    const float* pb1  = (const float*)d_in[5];
    const float* pwf  = (const float*)d_in[6];
    const float* pbf  = (const float*)d_in[7];
    float* out = (float*)d_out;

    float* K8T = (float*)d_ws;         // 200 floats (padded to 256)
    float* U0p = K8T + 256;            // PBUF floats: padded init
    float* Up  = U0p + PBUF;           // PBUF floats: padded u_n
    float* UHp = Up + PBUF;            // PBUF floats: padded u_half

    prep_kernel<<<dim3(1), dim3(256), 0, stream>>>(kern, K8T);
    pad_field<<<dim3((PBUF + 255)/256), dim3(256), 0, stream>>>(init, U0p);

    dim3 grid(3, 48, BATCH);           // 64x4 px tiles -> 2304 blocks
    dim3 block(256);

    // 5 RK2 midpoint steps = 10 sequential RHS evals.
    // s=0 reads padded init; in-place axpy on Up is safe (centers read only
    // by their owner thread; halos never read within a phase).
    rhs_phase<0><<<grid, block, 0, stream>>>(U0p, U0p, UHp, 0.1f, K8T, pw0,pb0,pw1,pb1,pwf,pbf);
    rhs_phase<1><<<grid, block, 0, stream>>>(UHp, U0p, Up,  0.2f, K8T, pw0,pb0,pw1,pb1,pwf,pbf);
    for (int s = 1; s < 4; ++s) {
        rhs_phase<0><<<grid, block, 0, stream>>>(Up,  Up, UHp, 0.1f, K8T, pw0,pb0,pw1,pb1,pwf,pbf);
        rhs_phase<1><<<grid, block, 0, stream>>>(UHp, Up, Up,  0.2f, K8T, pw0,pb0,pw1,pb1,pwf,pbf);
    }
    rhs_phase<0><<<grid, block, 0, stream>>>(Up,  Up, UHp, 0.1f, K8T, pw0,pb0,pw1,pb1,pwf,pbf);
    rhs_phase<2><<<grid, block, 0, stream>>>(UHp, Up, out, 0.2f, K8T, pw0,pb0,pw1,pb1,pwf,pbf);
}